// Round 9
// baseline (301.281 us; speedup 1.0000x reference)
//
#include <hip/hip_runtime.h>
#include <hip/hip_fp16.h>
#include <math.h>

#define N_NODES 100000
#define N_EDGES 1250000
#define D 64
#define EPS 1e-8f
#define GEMM_BLOCKS 2048

// ---------------------------------------------------------------------------
// hn[i,:] = normalize(tanh(x[i,:] @ W^T + b)) -> fp16. 2 rows/wave ILP.
// ---------------------------------------------------------------------------
__global__ __launch_bounds__(256) void k_gemm_norm(
    const float* __restrict__ x, const float* __restrict__ W,
    const float* __restrict__ b, __half* __restrict__ hn)
{
    __shared__ float xrow[4][160];
    const int lane = threadIdx.x & 63;
    const int wid  = threadIdx.x >> 6;

    float Wreg[64];
    const float4* Wv = (const float4*)(W + lane * D);
    #pragma unroll
    for (int q = 0; q < 16; ++q) {
        float4 w4 = Wv[q];
        Wreg[4*q+0] = w4.x; Wreg[4*q+1] = w4.y;
        Wreg[4*q+2] = w4.z; Wreg[4*q+3] = w4.w;
    }
    const float bj = b[lane];
    float* xl = xrow[wid];

    const int wave   = blockIdx.x * 4 + wid;
    const int nwaves = GEMM_BLOCKS * 4;

    for (int row = wave * 2; row < N_NODES; row += nwaves * 2) {
        const int row1 = row + 1;
        float xv0 = x[(size_t)row  * D + lane];
        float xv1 = x[(size_t)row1 * D + lane];
        xl[lane]      = xv0;
        xl[80 + lane] = xv1;
        float acc0 = bj, acc1 = bj;
        #pragma unroll
        for (int q = 0; q < 16; ++q) {
            float4 xa = *(const float4*)(xl + 4*q);
            float4 xb = *(const float4*)(xl + 80 + 4*q);
            acc0 = fmaf(xa.x, Wreg[4*q+0], acc0);
            acc1 = fmaf(xb.x, Wreg[4*q+0], acc1);
            acc0 = fmaf(xa.y, Wreg[4*q+1], acc0);
            acc1 = fmaf(xb.y, Wreg[4*q+1], acc1);
            acc0 = fmaf(xa.z, Wreg[4*q+2], acc0);
            acc1 = fmaf(xb.z, Wreg[4*q+2], acc1);
            acc0 = fmaf(xa.w, Wreg[4*q+3], acc0);
            acc1 = fmaf(xb.w, Wreg[4*q+3], acc1);
        }
        float h0 = tanhf(acc0);
        float h1 = tanhf(acc1);
        float s0 = h0 * h0, s1 = h1 * h1;
        #pragma unroll
        for (int m = 32; m >= 1; m >>= 1) {
            s0 += __shfl_xor(s0, m, 64);
            s1 += __shfl_xor(s1, m, 64);
        }
        hn[(size_t)row  * D + lane] = __float2half_rn(h0 / fmaxf(sqrtf(s0), EPS));
        hn[(size_t)row1 * D + lane] = __float2half_rn(h1 / fmaxf(sqrtf(s1), EPS));
    }
}

// ---------------------------------------------------------------------------
// The ONLY atomic pass: per-edge rank within destination node.
// ---------------------------------------------------------------------------
__global__ void k_rank(const int* __restrict__ ei, int* __restrict__ cnt,
                       int* __restrict__ rank)
{
    int e = blockIdx.x * 256 + threadIdx.x;
    if (e >= N_EDGES) return;
    int d = ei[N_EDGES + e];
    rank[e] = atomicAdd(cnt + d, 1);
}

// ---------------------------------------------------------------------------
// Scan: exclusive prefix sum of cnt -> rowptr
// ---------------------------------------------------------------------------
__device__ __forceinline__ int wave_iscan(int v, int lane)
{
    int incl = v;
    #pragma unroll
    for (int m = 1; m < 64; m <<= 1) {
        int o = __shfl_up(incl, m, 64);
        if (lane >= m) incl += o;
    }
    return incl;
}

__global__ __launch_bounds__(256) void k_scan1(
    const int* __restrict__ cnt, int* __restrict__ rowptr, int* __restrict__ bsum)
{
    __shared__ int wsum[4];
    int t = threadIdx.x, b = blockIdx.x;
    int i = b * 256 + t;
    int lane = t & 63, wid = t >> 6;
    int v = (i < N_NODES) ? cnt[i] : 0;
    int incl = wave_iscan(v, lane);
    if (lane == 63) wsum[wid] = incl;
    __syncthreads();
    int off = 0;
    #pragma unroll
    for (int k = 0; k < 4; ++k) if (k < wid) off += wsum[k];
    if (i < N_NODES) rowptr[i] = off + incl - v;
    if (t == 255) bsum[b] = off + incl;
}

__global__ __launch_bounds__(256) void k_scan23(
    int* __restrict__ rowptr, const int* __restrict__ bsum)
{
    __shared__ int wred[4];
    int b = blockIdx.x, t = threadIdx.x;
    int partial = 0;
    for (int j = t; j < b; j += 256) partial += bsum[j];
    #pragma unroll
    for (int m = 1; m < 64; m <<= 1) partial += __shfl_xor(partial, m, 64);
    if ((t & 63) == 0) wred[t >> 6] = partial;
    __syncthreads();
    int boff = wred[0] + wred[1] + wred[2] + wred[3];
    int i = b * 256 + t;
    if (i < N_NODES) rowptr[i] += boff;
    if (i == 0) rowptr[N_NODES] = N_EDGES;
}

// ---------------------------------------------------------------------------
// CSR placement: ONE 4B scattered store per edge (no atomics).
// ---------------------------------------------------------------------------
__global__ void k_place(
    const int* __restrict__ ei, const int* __restrict__ rank,
    const int* __restrict__ rowptr, int* __restrict__ srcs)
{
    int e = blockIdx.x * 256 + threadIdx.x;
    if (e >= N_EDGES) return;
    int s = ei[e];
    int d = ei[N_EDGES + e];
    srcs[rowptr[d] + rank[e]] = s;
}

// ---------------------------------------------------------------------------
// CSR-order cosine: one wave per node. hd row loaded ONCE per node (frag per
// lane, reused); 8 edges per wave-iteration (lane = edge(i>>3) x frag(i&7)).
// Writes wh coalesced fp16. Fused: deg reduce -> dis, y0.
// ---------------------------------------------------------------------------
__device__ __forceinline__ float dot8h(float4 a, float4 c)
{
    const __half2* ah = (const __half2*)&a;
    const __half2* ch = (const __half2*)&c;
    float p = 0.0f;
    #pragma unroll
    for (int q = 0; q < 4; ++q) {
        float2 af = __half22float2(ah[q]);
        float2 cf = __half22float2(ch[q]);
        p = fmaf(af.x, cf.x, p);
        p = fmaf(af.y, cf.y, p);
    }
    return p;
}

__global__ __launch_bounds__(256) void k_edge_cos(
    const __half* __restrict__ hn, const int* __restrict__ rowptr,
    const int* __restrict__ srcs, const float* __restrict__ mask,
    __half* __restrict__ wh, float* __restrict__ dis, float* __restrict__ y)
{
    const int i    = threadIdx.x & 63;
    const int node = (blockIdx.x * 256 + threadIdx.x) >> 6;
    if (node >= N_NODES) return;
    const int sub  = i >> 3;     // which of 8 edges this lane serves
    const int frag = i & 7;      // which float4 fragment of the row

    const float4 hd = ((const float4*)(hn + (size_t)node * D))[frag];
    const int beg = rowptr[node], end = rowptr[node + 1];

    float degacc = 0.0f;
    for (int base = beg; base < end; base += 8) {
        int eslot = base + sub;
        float w = 0.0f;
        if (eslot < end) {
            int s = srcs[eslot];
            float4 a = ((const float4*)(hn + (size_t)s * D))[frag];
            w = dot8h(a, hd);
        }
        w += __shfl_xor(w, 1, 64);
        w += __shfl_xor(w, 2, 64);
        w += __shfl_xor(w, 4, 64);
        if (frag == 0 && eslot < end) {
            w = fmaxf(w, 0.0f);
            wh[eslot] = __float2half_rn(w);
            degacc += w;
        }
    }
    // reduce degacc over lanes 0,8,...,56 (frag==0 lanes)
    degacc += __shfl_xor(degacc, 8, 64);
    degacc += __shfl_xor(degacc, 16, 64);
    degacc += __shfl_xor(degacc, 32, 64);
    if (i == 0) {
        float di = rsqrtf(fmaxf(degacc + 1.0f, EPS));   // +1 self-loop
        dis[node] = di;
        y[node] = di * fmaxf(mask[node], 0.0f);
    }
}

// ---------------------------------------------------------------------------
// APPNP step (16 lanes/node). Step-0 variant also recovers wout[e] in edge
// order via extra blocks (independent co-dispatched work).
// ---------------------------------------------------------------------------
__device__ __forceinline__ void spmv_body(
    int t, const int* __restrict__ rowptr, const int* __restrict__ srcs,
    const __half* __restrict__ wh, const float* __restrict__ y_in,
    const float* __restrict__ dis, const float* __restrict__ mask,
    float alpha, float* __restrict__ y_out, float* __restrict__ f_out)
{
    int node = t >> 4, l = t & 15;
    if (node >= N_NODES) return;
    int beg = rowptr[node], end = rowptr[node + 1];
    float sum = 0.0f;
    for (int j = beg + l; j < end; j += 16)
        sum += __half2float(wh[j]) * y_in[srcs[j]];
    sum += __shfl_xor(sum, 1, 64);
    sum += __shfl_xor(sum, 2, 64);
    sum += __shfl_xor(sum, 4, 64);
    sum += __shfl_xor(sum, 8, 64);
    if (l == 0) {
        float di = dis[node];
        float f0 = fmaxf(mask[node], 0.0f);
        float fn = (1.0f - alpha) * di * (sum + y_in[node]) + alpha * f0;
        f_out[node] = fn;
        y_out[node] = di * fn;
    }
}

#define SEG_BLOCKS 6250   // N_NODES*16/256

__global__ __launch_bounds__(256) void k_spmv0_wout(
    const int* __restrict__ rowptr, const int* __restrict__ srcs,
    const __half* __restrict__ wh, const float* __restrict__ y_in,
    const float* __restrict__ dis, const float* __restrict__ mask,
    const float* __restrict__ alpha_p, float* __restrict__ y_out,
    float* __restrict__ f_out,
    const int* __restrict__ ei, const int* __restrict__ rank,
    float* __restrict__ wout)
{
    if (blockIdx.x >= SEG_BLOCKS) {
        int e = (blockIdx.x - SEG_BLOCKS) * 256 + threadIdx.x;
        if (e < N_EDGES) {
            int d = ei[N_EDGES + e];
            wout[e] = __half2float(wh[rowptr[d] + rank[e]]);
        }
        return;
    }
    spmv_body(blockIdx.x * 256 + threadIdx.x, rowptr, srcs, wh, y_in, dis,
              mask, alpha_p[0], y_out, f_out);
}

__global__ __launch_bounds__(256) void k_spmv(
    const int* __restrict__ rowptr, const int* __restrict__ srcs,
    const __half* __restrict__ wh, const float* __restrict__ y_in,
    const float* __restrict__ dis, const float* __restrict__ mask,
    const float* __restrict__ alpha_p, float* __restrict__ y_out,
    float* __restrict__ f_out)
{
    spmv_body(blockIdx.x * 256 + threadIdx.x, rowptr, srcs, wh, y_in, dis,
              mask, alpha_p[0], y_out, f_out);
}

extern "C" void kernel_launch(void* const* d_in, const int* in_sizes, int n_in,
                              void* d_out, int out_size, void* d_ws, size_t ws_size,
                              hipStream_t stream)
{
    const float* x     = (const float*)d_in[0];
    const float* mask  = (const float*)d_in[1];
    const int*   ei    = (const int*)  d_in[2];
    const float* W     = (const float*)d_in[3];
    const float* b     = (const float*)d_in[4];
    const float* alpha = (const float*)d_in[5];

    float* out_f = (float*)d_out;
    float* out_w = (float*)d_out + N_NODES;

    // workspace layout (float-element offsets), ~27.3 MB
    float* ws = (float*)d_ws;
    __half* hn     = (__half*)ws;                  // 6.4M halves
    int*   srcs    = (int*)   (ws + 3200000);      // 1.25M
    __half* wh     = (__half*)(ws + 4450000);      // 1.25M halves
    int*   rank    = (int*)   (ws + 5075000);      // 1.25M
    int*   cnt     = (int*)   (ws + 6325000);      // 100k
    int*   rowptr  = (int*)   (ws + 6425000);      // 100001 (alloc 100016)
    float* dis     =           ws + 6525016;       // 100k
    float* y_a     =           ws + 6625016;       // 100k
    float* y_b     =           ws + 6725016;       // 100k
    int*   bsum    = (int*)   (ws + 6825016);      // 391 (alloc 512)

    const int nodeBlocks = (N_NODES + 255) / 256;        // 391
    const int edgeBlocks = (N_EDGES + 255) / 256;        // 4883
    const int cosBlocks  = (N_NODES * 64 + 255) / 256;   // 25000 (wave per node)

    hipMemsetAsync(cnt, 0, N_NODES * sizeof(int), stream);
    k_rank<<<edgeBlocks, 256, 0, stream>>>(ei, cnt, rank);
    k_gemm_norm<<<GEMM_BLOCKS, 256, 0, stream>>>(x, W, b, hn);
    k_scan1<<<nodeBlocks, 256, 0, stream>>>(cnt, rowptr, bsum);
    k_scan23<<<nodeBlocks, 256, 0, stream>>>(rowptr, bsum);
    k_place<<<edgeBlocks, 256, 0, stream>>>(ei, rank, rowptr, srcs);
    k_edge_cos<<<cosBlocks, 256, 0, stream>>>(hn, rowptr, srcs, mask, wh, dis, y_a);

    // step 0 (+ wout recovery co-dispatched), then steps 1..4
    k_spmv0_wout<<<SEG_BLOCKS + edgeBlocks, 256, 0, stream>>>(
        rowptr, srcs, wh, y_a, dis, mask, alpha, y_b, out_f, ei, rank, out_w);
    k_spmv<<<SEG_BLOCKS, 256, 0, stream>>>(rowptr, srcs, wh, y_b, dis, mask, alpha, y_a, out_f);
    k_spmv<<<SEG_BLOCKS, 256, 0, stream>>>(rowptr, srcs, wh, y_a, dis, mask, alpha, y_b, out_f);
    k_spmv<<<SEG_BLOCKS, 256, 0, stream>>>(rowptr, srcs, wh, y_b, dis, mask, alpha, y_a, out_f);
    k_spmv<<<SEG_BLOCKS, 256, 0, stream>>>(rowptr, srcs, wh, y_a, dis, mask, alpha, y_b, out_f);
}

// Round 10
// 295.824 us; speedup vs baseline: 1.0184x; 1.0184x over previous
//
#include <hip/hip_runtime.h>
#include <hip/hip_fp16.h>
#include <math.h>

#define N_NODES 100000
#define N_EDGES 1250000
#define D 64
#define EPS 1e-8f
#define GEMM_BLOCKS 2048

// ---------------------------------------------------------------------------
// Fused dispatch: blocks [0,GEMM_BLOCKS) = gemm+normalize -> fp16 hn;
// blocks >= GEMM_BLOCKS = rank pass (the ONLY scattered atomics, 2 edges/thr).
// Rank waves idle on atomic returns; gemm waves fill the VALU underneath.
// ---------------------------------------------------------------------------
__global__ __launch_bounds__(256) void k_gemm_rank(
    const float* __restrict__ x, const float* __restrict__ W,
    const float* __restrict__ b, __half* __restrict__ hn,
    const int* __restrict__ ei, int* __restrict__ cnt, int* __restrict__ rank)
{
    if (blockIdx.x >= GEMM_BLOCKS) {
        int e0 = (blockIdx.x - GEMM_BLOCKS) * 512 + threadIdx.x;
        int e1 = e0 + 256;
        if (e0 < N_EDGES) {
            int d0 = ei[N_EDGES + e0];
            rank[e0] = atomicAdd(cnt + d0, 1);
        }
        if (e1 < N_EDGES) {
            int d1 = ei[N_EDGES + e1];
            rank[e1] = atomicAdd(cnt + d1, 1);
        }
        return;
    }

    __shared__ float xrow[4][160];
    const int lane = threadIdx.x & 63;
    const int wid  = threadIdx.x >> 6;

    float Wreg[64];
    const float4* Wv = (const float4*)(W + lane * D);
    #pragma unroll
    for (int q = 0; q < 16; ++q) {
        float4 w4 = Wv[q];
        Wreg[4*q+0] = w4.x; Wreg[4*q+1] = w4.y;
        Wreg[4*q+2] = w4.z; Wreg[4*q+3] = w4.w;
    }
    const float bj = b[lane];
    float* xl = xrow[wid];

    const int wave   = blockIdx.x * 4 + wid;
    const int nwaves = GEMM_BLOCKS * 4;

    for (int row = wave * 2; row < N_NODES; row += nwaves * 2) {
        const int row1 = row + 1;
        float xv0 = x[(size_t)row  * D + lane];
        float xv1 = x[(size_t)row1 * D + lane];
        xl[lane]      = xv0;
        xl[80 + lane] = xv1;
        float acc0 = bj, acc1 = bj;
        #pragma unroll
        for (int q = 0; q < 16; ++q) {
            float4 xa = *(const float4*)(xl + 4*q);
            float4 xb = *(const float4*)(xl + 80 + 4*q);
            acc0 = fmaf(xa.x, Wreg[4*q+0], acc0);
            acc1 = fmaf(xb.x, Wreg[4*q+0], acc1);
            acc0 = fmaf(xa.y, Wreg[4*q+1], acc0);
            acc1 = fmaf(xb.y, Wreg[4*q+1], acc1);
            acc0 = fmaf(xa.z, Wreg[4*q+2], acc0);
            acc1 = fmaf(xb.z, Wreg[4*q+2], acc1);
            acc0 = fmaf(xa.w, Wreg[4*q+3], acc0);
            acc1 = fmaf(xb.w, Wreg[4*q+3], acc1);
        }
        float h0 = tanhf(acc0);
        float h1 = tanhf(acc1);
        float s0 = h0 * h0, s1 = h1 * h1;
        #pragma unroll
        for (int m = 32; m >= 1; m >>= 1) {
            s0 += __shfl_xor(s0, m, 64);
            s1 += __shfl_xor(s1, m, 64);
        }
        hn[(size_t)row  * D + lane] = __float2half_rn(h0 / fmaxf(sqrtf(s0), EPS));
        hn[(size_t)row1 * D + lane] = __float2half_rn(h1 / fmaxf(sqrtf(s1), EPS));
    }
}

// ---------------------------------------------------------------------------
// Scan: exclusive prefix sum of cnt -> rowptr
// ---------------------------------------------------------------------------
__device__ __forceinline__ int wave_iscan(int v, int lane)
{
    int incl = v;
    #pragma unroll
    for (int m = 1; m < 64; m <<= 1) {
        int o = __shfl_up(incl, m, 64);
        if (lane >= m) incl += o;
    }
    return incl;
}

__global__ __launch_bounds__(256) void k_scan1(
    const int* __restrict__ cnt, int* __restrict__ rowptr, int* __restrict__ bsum)
{
    __shared__ int wsum[4];
    int t = threadIdx.x, b = blockIdx.x;
    int i = b * 256 + t;
    int lane = t & 63, wid = t >> 6;
    int v = (i < N_NODES) ? cnt[i] : 0;
    int incl = wave_iscan(v, lane);
    if (lane == 63) wsum[wid] = incl;
    __syncthreads();
    int off = 0;
    #pragma unroll
    for (int k = 0; k < 4; ++k) if (k < wid) off += wsum[k];
    if (i < N_NODES) rowptr[i] = off + incl - v;
    if (t == 255) bsum[b] = off + incl;
}

__global__ __launch_bounds__(256) void k_scan23(
    int* __restrict__ rowptr, const int* __restrict__ bsum)
{
    __shared__ int wred[4];
    int b = blockIdx.x, t = threadIdx.x;
    int partial = 0;
    for (int j = t; j < b; j += 256) partial += bsum[j];
    #pragma unroll
    for (int m = 1; m < 64; m <<= 1) partial += __shfl_xor(partial, m, 64);
    if ((t & 63) == 0) wred[t >> 6] = partial;
    __syncthreads();
    int boff = wred[0] + wred[1] + wred[2] + wred[3];
    int i = b * 256 + t;
    if (i < N_NODES) rowptr[i] += boff;
    if (i == 0) rowptr[N_NODES] = N_EDGES;
}

// ---------------------------------------------------------------------------
// CSR placement: ONE 4B scattered store per edge (no atomics).
// ---------------------------------------------------------------------------
__global__ void k_place(
    const int* __restrict__ ei, const int* __restrict__ rank,
    const int* __restrict__ rowptr, int* __restrict__ srcs)
{
    int e = blockIdx.x * 256 + threadIdx.x;
    if (e >= N_EDGES) return;
    int s = ei[e];
    int d = ei[N_EDGES + e];
    srcs[rowptr[d] + rank[e]] = s;
}

// ---------------------------------------------------------------------------
// CSR-order cosine: one wave per node; 4 lanes/edge x 2 float4/lane ->
// 16 edges in flight per iteration. hd loaded once/node. Coalesced wh write.
// Fused: deg reduce -> dis, y0.
// ---------------------------------------------------------------------------
__device__ __forceinline__ float dot8h(float4 a, float4 c)
{
    const __half2* ah = (const __half2*)&a;
    const __half2* ch = (const __half2*)&c;
    float p = 0.0f;
    #pragma unroll
    for (int q = 0; q < 4; ++q) {
        float2 af = __half22float2(ah[q]);
        float2 cf = __half22float2(ch[q]);
        p = fmaf(af.x, cf.x, p);
        p = fmaf(af.y, cf.y, p);
    }
    return p;
}

__global__ __launch_bounds__(256) void k_edge_cos(
    const __half* __restrict__ hn, const int* __restrict__ rowptr,
    const int* __restrict__ srcs, const float* __restrict__ mask,
    __half* __restrict__ wh, float* __restrict__ dis, float* __restrict__ y)
{
    const int i    = threadIdx.x & 63;
    const int node = (blockIdx.x * 256 + threadIdx.x) >> 6;
    if (node >= N_NODES) return;
    const int sub  = i >> 2;     // which of 16 edges this lane serves
    const int frag = i & 3;      // fragments frag and frag+4 of the row

    const float4* hrow = (const float4*)(hn + (size_t)node * D);
    const float4 hd0 = hrow[frag];
    const float4 hd1 = hrow[frag + 4];
    const int beg = rowptr[node], end = rowptr[node + 1];

    float degacc = 0.0f;
    for (int base = beg; base < end; base += 16) {
        int eslot = base + sub;
        float w = 0.0f;
        if (eslot < end) {
            int s = srcs[eslot];
            const float4* arow = (const float4*)(hn + (size_t)s * D);
            w = dot8h(arow[frag], hd0) + dot8h(arow[frag + 4], hd1);
        }
        w += __shfl_xor(w, 1, 64);
        w += __shfl_xor(w, 2, 64);
        if (frag == 0 && eslot < end) {
            w = fmaxf(w, 0.0f);
            wh[eslot] = __float2half_rn(w);
            degacc += w;
        }
    }
    degacc += __shfl_xor(degacc, 4, 64);
    degacc += __shfl_xor(degacc, 8, 64);
    degacc += __shfl_xor(degacc, 16, 64);
    degacc += __shfl_xor(degacc, 32, 64);
    if (i == 0) {
        float di = rsqrtf(fmaxf(degacc + 1.0f, EPS));   // +1 self-loop
        dis[node] = di;
        y[node] = di * fmaxf(mask[node], 0.0f);
    }
}

// ---------------------------------------------------------------------------
// APPNP step (16 lanes/node). Step-0 variant also recovers wout[e] in edge
// order via extra co-dispatched blocks.
// ---------------------------------------------------------------------------
__device__ __forceinline__ void spmv_body(
    int t, const int* __restrict__ rowptr, const int* __restrict__ srcs,
    const __half* __restrict__ wh, const float* __restrict__ y_in,
    const float* __restrict__ dis, const float* __restrict__ mask,
    float alpha, float* __restrict__ y_out, float* __restrict__ f_out)
{
    int node = t >> 4, l = t & 15;
    if (node >= N_NODES) return;
    int beg = rowptr[node], end = rowptr[node + 1];
    float sum = 0.0f;
    for (int j = beg + l; j < end; j += 16)
        sum += __half2float(wh[j]) * y_in[srcs[j]];
    sum += __shfl_xor(sum, 1, 64);
    sum += __shfl_xor(sum, 2, 64);
    sum += __shfl_xor(sum, 4, 64);
    sum += __shfl_xor(sum, 8, 64);
    if (l == 0) {
        float di = dis[node];
        float f0 = fmaxf(mask[node], 0.0f);
        float fn = (1.0f - alpha) * di * (sum + y_in[node]) + alpha * f0;
        f_out[node] = fn;
        y_out[node] = di * fn;
    }
}

#define SEG_BLOCKS 6250   // N_NODES*16/256

__global__ __launch_bounds__(256) void k_spmv0_wout(
    const int* __restrict__ rowptr, const int* __restrict__ srcs,
    const __half* __restrict__ wh, const float* __restrict__ y_in,
    const float* __restrict__ dis, const float* __restrict__ mask,
    const float* __restrict__ alpha_p, float* __restrict__ y_out,
    float* __restrict__ f_out,
    const int* __restrict__ ei, const int* __restrict__ rank,
    float* __restrict__ wout)
{
    if (blockIdx.x >= SEG_BLOCKS) {
        int e = (blockIdx.x - SEG_BLOCKS) * 256 + threadIdx.x;
        if (e < N_EDGES) {
            int d = ei[N_EDGES + e];
            wout[e] = __half2float(wh[rowptr[d] + rank[e]]);
        }
        return;
    }
    spmv_body(blockIdx.x * 256 + threadIdx.x, rowptr, srcs, wh, y_in, dis,
              mask, alpha_p[0], y_out, f_out);
}

__global__ __launch_bounds__(256) void k_spmv(
    const int* __restrict__ rowptr, const int* __restrict__ srcs,
    const __half* __restrict__ wh, const float* __restrict__ y_in,
    const float* __restrict__ dis, const float* __restrict__ mask,
    const float* __restrict__ alpha_p, float* __restrict__ y_out,
    float* __restrict__ f_out)
{
    spmv_body(blockIdx.x * 256 + threadIdx.x, rowptr, srcs, wh, y_in, dis,
              mask, alpha_p[0], y_out, f_out);
}

extern "C" void kernel_launch(void* const* d_in, const int* in_sizes, int n_in,
                              void* d_out, int out_size, void* d_ws, size_t ws_size,
                              hipStream_t stream)
{
    const float* x     = (const float*)d_in[0];
    const float* mask  = (const float*)d_in[1];
    const int*   ei    = (const int*)  d_in[2];
    const float* W     = (const float*)d_in[3];
    const float* b     = (const float*)d_in[4];
    const float* alpha = (const float*)d_in[5];

    float* out_f = (float*)d_out;
    float* out_w = (float*)d_out + N_NODES;

    // workspace layout (float-element offsets), ~27.3 MB
    float* ws = (float*)d_ws;
    __half* hn     = (__half*)ws;                  // 6.4M halves
    int*   srcs    = (int*)   (ws + 3200000);      // 1.25M
    __half* wh     = (__half*)(ws + 4450000);      // 1.25M halves
    int*   rank    = (int*)   (ws + 5075000);      // 1.25M
    int*   cnt     = (int*)   (ws + 6325000);      // 100k
    int*   rowptr  = (int*)   (ws + 6425000);      // 100001 (alloc 100016)
    float* dis     =           ws + 6525016;       // 100k
    float* y_a     =           ws + 6625016;       // 100k
    float* y_b     =           ws + 6725016;       // 100k
    int*   bsum    = (int*)   (ws + 6825016);      // 391 (alloc 512)

    const int nodeBlocks = (N_NODES + 255) / 256;        // 391
    const int edgeBlocks = (N_EDGES + 255) / 256;        // 4883
    const int rankBlocks = (N_EDGES + 511) / 512;        // 2442 (2 edges/thread)
    const int cosBlocks  = (N_NODES * 64 + 255) / 256;   // 25000 (wave per node)

    hipMemsetAsync(cnt, 0, N_NODES * sizeof(int), stream);
    k_gemm_rank<<<GEMM_BLOCKS + rankBlocks, 256, 0, stream>>>(x, W, b, hn, ei, cnt, rank);
    k_scan1<<<nodeBlocks, 256, 0, stream>>>(cnt, rowptr, bsum);
    k_scan23<<<nodeBlocks, 256, 0, stream>>>(rowptr, bsum);
    k_place<<<edgeBlocks, 256, 0, stream>>>(ei, rank, rowptr, srcs);
    k_edge_cos<<<cosBlocks, 256, 0, stream>>>(hn, rowptr, srcs, mask, wh, dis, y_a);

    // step 0 (+ wout recovery co-dispatched), then steps 1..4
    k_spmv0_wout<<<SEG_BLOCKS + edgeBlocks, 256, 0, stream>>>(
        rowptr, srcs, wh, y_a, dis, mask, alpha, y_b, out_f, ei, rank, out_w);
    k_spmv<<<SEG_BLOCKS, 256, 0, stream>>>(rowptr, srcs, wh, y_b, dis, mask, alpha, y_a, out_f);
    k_spmv<<<SEG_BLOCKS, 256, 0, stream>>>(rowptr, srcs, wh, y_a, dis, mask, alpha, y_b, out_f);
    k_spmv<<<SEG_BLOCKS, 256, 0, stream>>>(rowptr, srcs, wh, y_b, dis, mask, alpha, y_a, out_f);
    k_spmv<<<SEG_BLOCKS, 256, 0, stream>>>(rowptr, srcs, wh, y_a, dis, mask, alpha, y_b, out_f);
}